// Round 10
// baseline (697.563 us; speedup 1.0000x reference)
//
#include <hip/hip_runtime.h>
#include <hip/hip_bf16.h>
#include <math.h>

#define B_Q 2048
#define N_K 131072
#define D_DIM 256
#define NCHUNK 32
#define CHUNK_KEYS (N_K / NCHUNK)    // 4096
#define KTILE 32
#define NITER (CHUNK_KEYS / KTILE)   // 128
#define NTILES (N_K / KTILE)         // 4096
#define TILE_USHORTS 16384           // 32 KB per tile: 16KB K fp16 + 16KB V bf16
#define LOG2E 1.44269504f
#define NBLK 512

typedef __attribute__((ext_vector_type(8))) _Float16 half8;   // 4 VGPRs
typedef __attribute__((ext_vector_type(8))) short bf16x8;     // 4 VGPRs
typedef __attribute__((ext_vector_type(4))) short bf16x4;
typedef __attribute__((ext_vector_type(2))) __fp16 fp16x2;
typedef __attribute__((ext_vector_type(4))) float f32x4;
typedef __attribute__((ext_vector_type(16))) float f32x16;

static __device__ __forceinline__ unsigned pkrtz(float a, float b) {
    fp16x2 h = __builtin_amdgcn_cvt_pkrtz(a, b);
    return __builtin_bit_cast(unsigned, h);
}
static __device__ __forceinline__ unsigned short f2bf(float f) {
    unsigned u = __builtin_bit_cast(unsigned, f);
    unsigned r = (u + 0x7fffu + ((u >> 16) & 1u)) >> 16;   // RNE
    return (unsigned short)r;
}
// packed f32x2 -> bf16x2 (lo=first arg), single VALU op (no builtin on gfx950)
static __device__ __forceinline__ unsigned cvt_pk_bf16(float lo, float hi) {
    unsigned d;
    asm("v_cvt_pk_bf16_f32 %0, %1, %2" : "=v"(d) : "v"(lo), "v"(hi));
    return d;
}

typedef const __attribute__((address_space(1))) unsigned int* gas_p;
typedef __attribute__((address_space(3))) unsigned int* las_p;
static __device__ __forceinline__ void gl_lds16(const void* g, void* l) {
    __builtin_amdgcn_global_load_lds((gas_p)g, (las_p)l, 16, 0, 0);
}

// ---------------------------------------------------------------------------
// Manual grid barrier (graph-capturable; hipLaunchCooperativeKernel is NOT --
// R9's launch silently failed under graph capture, output stayed memset-0).
// Correctness under per-XCD non-coherent L2s: all barrier traffic uses
// __hip_atomic_* at AGENT scope (acquire/release -> compiler emits the
// cross-XCD cache ops); __threadfence() before arrival publishes this block's
// plain stores; the acquire spin-load invalidates before consumption.
// Co-residency: LDS 64KB/block -> exactly 2 blocks/CU -> 512 slots = grid, and
// blocks parked here never retire, so the CP fills all slots. Counters are
// zeroed each launch by a captured hipMemsetAsync.
// ---------------------------------------------------------------------------
static __device__ __forceinline__ void grid_barrier(unsigned* bar) {
    __syncthreads();
    if (threadIdx.x == 0) {
        __threadfence();   // publish prior writes device-wide
        unsigned prev = __hip_atomic_fetch_add(&bar[0], 1u, __ATOMIC_ACQ_REL,
                                               __HIP_MEMORY_SCOPE_AGENT);
        if (prev == NBLK - 1) {
            __hip_atomic_store(&bar[16], 1u, __ATOMIC_RELEASE,
                               __HIP_MEMORY_SCOPE_AGENT);
        } else {
            while (__hip_atomic_load(&bar[16], __ATOMIC_ACQUIRE,
                                     __HIP_MEMORY_SCOPE_AGENT) == 0u) {
                __builtin_amdgcn_s_sleep(8);
            }
        }
        __threadfence();
    }
    __syncthreads();
}

// ---------------------------------------------------------------------------
// R10: single fused kernel, grid 512 x 256 (2 blocks/CU by 64KB LDS).
// Phase A (LDS-free prepass, R8) -> grid_barrier -> Phase B (main, frozen
// 269-275us schedule) -> grid_barrier -> Phase C (combine).
//
// Phase A: stored [N][256] fp32 -> per-32-key-tile fragment blob (32 KB):
//   K (fp16 RTZ, PRE-SCALED by log2e; main does p=exp2(S), M0 folded into
//   accumulator init): pos (s*64+l)*8+j <- log2e*stored[t*32+(l&31)][16s+(l>>5)*8+j]
//   V (bf16 -- NOT fp16: P's range hits fp16's subnormal cliff):
//     pos 8192+((dn*2+ks)*64+l)*8+j <- stored[t*32+16ks+(l>>5)*8+j][32dn+(l&31)]
// Phase B: 4 waves x 32 q; swapped-QK 32x32; softmax in-register
//   (cvt_pk+permlane); K/V double-buffered via gl_lds(16B); barrier ->
//   prefetch -> QK [S init=-M0L] -> sm-half0 -> PV-A -> sm-half1 -> PV-B.
//   Register wall: 256 regs/wave, zero headroom (R2/R3/R7 regressions).
// Phase C: 4 q/block, bf16x4 loads, f32x4 store.
// ---------------------------------------------------------------------------
__global__ __launch_bounds__(256, 2)
void hopfield_fused(const float* __restrict__ x,
                    const float* __restrict__ stored,
                    unsigned short* __restrict__ frag,
                    unsigned short* __restrict__ partOb,
                    float* __restrict__ partl,
                    float* __restrict__ out,
                    unsigned* __restrict__ bars) {
    __shared__ __align__(16) unsigned short Kb[2][8192];   // 2 x 16 KB
    __shared__ __align__(16) unsigned short Vb[2][8192];   // 2 x 16 KB

    const int tid = threadIdx.x;
    const int blk = blockIdx.x;

    // ================= Phase A: prepass, 8 tiles per block =================
#pragma unroll 1
    for (int tt = 0; tt < 8; ++tt) {
        const int t = blk * 8 + tt;
        const float* src = stored + (size_t)t * 32 * 256;
        unsigned short* outp = frag + (size_t)t * TILE_USHORTS;
        // K region (fp16, x log2e): 1024 cells of 16B, cell ck = (s, lane)
#pragma unroll
        for (int i = 0; i < 4; ++i) {
            int ck = i * 256 + tid;
            int l = ck & 63, s = ck >> 6;
            int key = l & 31, h = l >> 5;
            int d0 = s * 16 + h * 8;
            const float* p = src + key * 256 + d0;
            f32x4 a = *(const f32x4*)p;
            f32x4 b = *(const f32x4*)(p + 4);
            union { uint4 v; unsigned e[4]; } o;
            o.e[0] = pkrtz(a[0] * LOG2E, a[1] * LOG2E);
            o.e[1] = pkrtz(a[2] * LOG2E, a[3] * LOG2E);
            o.e[2] = pkrtz(b[0] * LOG2E, b[1] * LOG2E);
            o.e[3] = pkrtz(b[2] * LOG2E, b[3] * LOG2E);
            *(uint4*)(outp + ck * 8) = o.v;
        }
        // V region (bf16): 1024 cells, cell cv = (dn, ks, lane)
#pragma unroll
        for (int i = 0; i < 4; ++i) {
            int cv = i * 256 + tid;
            int l = cv & 63, blkv = cv >> 6;
            int dn = blkv >> 1, ks = blkv & 1;
            int colv = l & 31, h = l >> 5;
            int d = dn * 32 + colv;
            int k0 = ks * 16 + h * 8;
            union { uint4 v; unsigned e[4]; } o;
#pragma unroll
            for (int j2 = 0; j2 < 4; ++j2) {
                float v0 = src[(k0 + 2 * j2) * 256 + d];
                float v1 = src[(k0 + 2 * j2 + 1) * 256 + d];
                o.e[j2] = cvt_pk_bf16(v0, v1);      // lo=v0, hi=v1
            }
            *(uint4*)(outp + 8192 + cv * 8) = o.v;
        }
    }

    grid_barrier(bars);        // frag visible device-wide

    // ========================== Phase B: main ==============================
    {
        const int wave = tid >> 6, lane = tid & 63;
        const int col = lane & 31, hf = lane >> 5;
        const int chunk = blk & 31, qb = blk >> 5;
        const int q0w = qb * 128 + wave * 32;
        const unsigned short* fbase = frag + (size_t)chunk * NITER * TILE_USHORTS;

        // ---- x fragments (fp16, B-operand: X[q=col][d=16s+8*hf+j]) ----
        half8 xf[16];
        float ss = 0.f;
        {
            const float* xr = x + (size_t)(q0w + col) * 256 + hf * 8;
#pragma unroll
            for (int s = 0; s < 16; ++s) {
                f32x4 a = *(const f32x4*)(xr + s * 16);
                f32x4 b = *(const f32x4*)(xr + s * 16 + 4);
                union { half8 v; _Float16 e[8]; } h;
#pragma unroll
                for (int j = 0; j < 4; ++j) {
                    h.e[j] = (_Float16)a[j]; h.e[4 + j] = (_Float16)b[j];
                    ss += a[j] * a[j] + b[j] * b[j];
                }
                xf[s] = h.v;
            }
        }
        ss += __shfl_xor(ss, 32);             // lane covers 128 dims; fold halves
        const float negM0L = -(4.9f * sqrtf(ss) * LOG2E);  // S-accumulator init

        f32x16 O[8];
        const f32x16 z16 = {0.f,0.f,0.f,0.f,0.f,0.f,0.f,0.f,
                            0.f,0.f,0.f,0.f,0.f,0.f,0.f,0.f};
#pragma unroll
        for (int dn = 0; dn < 8; ++dn) O[dn] = z16;
        float lacc = 0.f;

        // preload K(0), V(0) into buffer 0 (16 x 1KB chunks each; wave does 4)
#pragma unroll
        for (int j = 0; j < 4; ++j) {
            int off = (wave * 4 + j) * 512 + lane * 8;
            gl_lds16(fbase + off, &Kb[0][off]);
            gl_lds16(fbase + 8192 + off, &Vb[0][off]);
        }

#pragma unroll 1
        for (int it = 0; it < NITER; ++it) {
            __syncthreads();   // K(it),V(it) staged; prev iter's readers done

            if (it + 1 < NITER) {
                const unsigned short* nbase = fbase + (size_t)(it + 1) * TILE_USHORTS;
#pragma unroll
                for (int j = 0; j < 4; ++j) {
                    int off = (wave * 4 + j) * 512 + lane * 8;
                    gl_lds16(nbase + off, &Kb[(it + 1) & 1][off]);
                    gl_lds16(nbase + 8192 + off, &Vb[(it + 1) & 1][off]);
                }
            }

            const unsigned short* K = Kb[it & 1];
            const unsigned short* V = Vb[it & 1];

            // ---- QK(it): S^T[32k][32q]; S init = -M0L (shift folded in) ----
            f32x16 S;
#pragma unroll
            for (int r = 0; r < 16; ++r) S[r] = negM0L;
            __builtin_amdgcn_s_setprio(1);
#pragma unroll
            for (int s = 0; s < 16; ++s) {
                half8 af = *(const half8*)(K + (s * 64 + lane) * 8);
                S = __builtin_amdgcn_mfma_f32_32x32x16_f16(af, xf[s], S, 0, 0, 0);
            }
            __builtin_amdgcn_s_setprio(0);

            // ---- softmax half0: keys 0..15 (S[0..7]) -> pa0 ----
            // w[r2] packs keys {2*(r2&1)+8*(r2>>1)+4*hf, +1}; permlane32_swap
            // -> a'=(a_lo,b_lo), b'=(a_hi,b_hi): pa regs exactly (verified R1).
            float p0[8];
#pragma unroll
            for (int r = 0; r < 8; ++r) p0[r] = __builtin_amdgcn_exp2f(S[r]);
            lacc += ((p0[0] + p0[1]) + (p0[2] + p0[3])) + ((p0[4] + p0[5]) + (p0[6] + p0[7]));
            unsigned w0 = cvt_pk_bf16(p0[0], p0[1]);
            unsigned w1 = cvt_pk_bf16(p0[2], p0[3]);
            unsigned w2 = cvt_pk_bf16(p0[4], p0[5]);
            unsigned w3 = cvt_pk_bf16(p0[6], p0[7]);
            asm volatile("v_permlane32_swap_b32 %0, %1" : "+v"(w0), "+v"(w2));
            asm volatile("v_permlane32_swap_b32 %0, %1" : "+v"(w1), "+v"(w3));
            union { bf16x8 v; unsigned u[4]; } A0;
            A0.u[0] = w0; A0.u[1] = w1; A0.u[2] = w2; A0.u[3] = w3;
            bf16x8 pa0 = A0.v;

            // ---- PV-A: ks=0 V-frags; half1 VALU overlaps this MFMA run ----
            __builtin_amdgcn_s_setprio(1);
#pragma unroll
            for (int dn = 0; dn < 8; ++dn) {
                bf16x8 bv0 = *(const bf16x8*)(V + ((dn * 2 + 0) * 64 + lane) * 8);
                O[dn] = __builtin_amdgcn_mfma_f32_32x32x16_bf16(pa0, bv0, O[dn], 0, 0, 0);
            }
            __builtin_amdgcn_s_setprio(0);

            // ---- softmax half1: keys 16..31 (S[8..15]) -> pa1 ----
            float p1[8];
#pragma unroll
            for (int r = 0; r < 8; ++r) p1[r] = __builtin_amdgcn_exp2f(S[8 + r]);
            lacc += ((p1[0] + p1[1]) + (p1[2] + p1[3])) + ((p1[4] + p1[5]) + (p1[6] + p1[7]));
            unsigned w4 = cvt_pk_bf16(p1[0], p1[1]);
            unsigned w5 = cvt_pk_bf16(p1[2], p1[3]);
            unsigned w6 = cvt_pk_bf16(p1[4], p1[5]);
            unsigned w7 = cvt_pk_bf16(p1[6], p1[7]);
            asm volatile("v_permlane32_swap_b32 %0, %1" : "+v"(w4), "+v"(w6));
            asm volatile("v_permlane32_swap_b32 %0, %1" : "+v"(w5), "+v"(w7));
            union { bf16x8 v; unsigned u[4]; } A1;
            A1.u[0] = w4; A1.u[1] = w5; A1.u[2] = w6; A1.u[3] = w7;
            bf16x8 pa1 = A1.v;

            // ---- PV-B: ks=1 V-frags ----
            __builtin_amdgcn_s_setprio(1);
#pragma unroll
            for (int dn = 0; dn < 8; ++dn) {
                bf16x8 bv1 = *(const bf16x8*)(V + ((dn * 2 + 1) * 64 + lane) * 8);
                O[dn] = __builtin_amdgcn_mfma_f32_32x32x16_bf16(pa1, bv1, O[dn], 0, 0, 0);
            }
            __builtin_amdgcn_s_setprio(0);
        }

        // ---- epilogue: l then O as bf16 (row q=(r&3)+8*(r>>2)+4*hf) ----
        lacc += __shfl_xor(lacc, 32);
        if (lane < 32)
            partl[(size_t)chunk * B_Q + q0w + lane] = lacc;

#pragma unroll
        for (int dn = 0; dn < 8; ++dn)
#pragma unroll
            for (int r = 0; r < 16; ++r) {
                int qrow = (r & 3) + 8 * (r >> 2) + 4 * hf;
                partOb[((size_t)chunk * B_Q + q0w + qrow) * 256 + dn * 32 + col] = f2bf(O[dn][r]);
            }
    }

    grid_barrier(bars + 64);   // all partials visible device-wide

    // ========================= Phase C: combine ============================
    {
        const int ql = tid >> 6;                 // 0..3
        const int q  = blk * 4 + ql;
        const int d0 = (tid & 63) * 4;
        float L = 0.f;
#pragma unroll
        for (int c = 0; c < NCHUNK; ++c) L += partl[(size_t)c * B_Q + q];
        float acc[4] = {0.f, 0.f, 0.f, 0.f};
#pragma unroll 4
        for (int c = 0; c < NCHUNK; ++c) {
            bf16x4 v = *(const bf16x4*)(partOb + ((size_t)c * B_Q + q) * 256 + d0);
#pragma unroll
            for (int j = 0; j < 4; ++j) {
                unsigned u = (unsigned)(unsigned short)v[j] << 16;
                acc[j] += __builtin_bit_cast(float, u);
            }
        }
        const float invL = 1.f / L;
        f32x4 o = {acc[0] * invL, acc[1] * invL, acc[2] * invL, acc[3] * invL};
        *(f32x4*)(out + (size_t)q * 256 + d0) = o;
    }
}

// ---------------------------------------------------------------------------
extern "C" void kernel_launch(void* const* d_in, const int* in_sizes, int n_in,
                              void* d_out, int out_size, void* d_ws, size_t ws_size,
                              hipStream_t stream) {
    const float* x      = (const float*)d_in[0];
    const float* stored = (const float*)d_in[1];
    float* out = (float*)d_out;

    char* wsb = (char*)d_ws;
    unsigned short* frag   = (unsigned short*)wsb;                       // 128 MiB
    unsigned short* partOb = (unsigned short*)(wsb + (size_t)134217728); // 32 MiB (bf16)
    float* partl = (float*)(wsb + (size_t)134217728 + 33554432);         // 256 KiB
    unsigned* bars = (unsigned*)(wsb + (size_t)134217728 + 33554432 + 262144);

    // zero the two barrier slots (captured into the graph, replayed per iter)
    hipMemsetAsync(bars, 0, 512, stream);
    hopfield_fused<<<NBLK, 256, 0, stream>>>(x, stored, frag, partOb, partl, out, bars);
}

// Round 11
// 463.254 us; speedup vs baseline: 1.5058x; 1.5058x over previous
//
#include <hip/hip_runtime.h>
#include <hip/hip_bf16.h>
#include <math.h>

#define B_Q 2048
#define N_K 131072
#define D_DIM 256
#define NCHUNK 32
#define CHUNK_KEYS (N_K / NCHUNK)    // 4096
#define KTILE 32
#define NITER (CHUNK_KEYS / KTILE)   // 128
#define NTILES (N_K / KTILE)         // 4096
#define TILE_USHORTS 16384           // 32 KB per tile: 16KB K fp16 + 16KB V bf16
#define LOG2E 1.44269504f

typedef __attribute__((ext_vector_type(8))) _Float16 half8;   // 4 VGPRs
typedef __attribute__((ext_vector_type(8))) short bf16x8;     // 4 VGPRs
typedef __attribute__((ext_vector_type(4))) short bf16x4;
typedef __attribute__((ext_vector_type(2))) __fp16 fp16x2;
typedef __attribute__((ext_vector_type(4))) float f32x4;
typedef __attribute__((ext_vector_type(16))) float f32x16;

static __device__ __forceinline__ unsigned pkrtz(float a, float b) {
    fp16x2 h = __builtin_amdgcn_cvt_pkrtz(a, b);
    return __builtin_bit_cast(unsigned, h);
}
static __device__ __forceinline__ unsigned short f2bf(float f) {
    unsigned u = __builtin_bit_cast(unsigned, f);
    unsigned r = (u + 0x7fffu + ((u >> 16) & 1u)) >> 16;   // RNE
    return (unsigned short)r;
}
// packed f32x2 -> bf16x2 (lo=first arg), single VALU op (no builtin on gfx950)
static __device__ __forceinline__ unsigned cvt_pk_bf16(float lo, float hi) {
    unsigned d;
    asm("v_cvt_pk_bf16_f32 %0, %1, %2" : "=v"(d) : "v"(lo), "v"(hi));
    return d;
}

typedef const __attribute__((address_space(1))) unsigned int* gas_p;
typedef __attribute__((address_space(3))) unsigned int* las_p;
static __device__ __forceinline__ void gl_lds16(const void* g, void* l) {
    __builtin_amdgcn_global_load_lds((gas_p)g, (las_p)l, 16, 0, 0);
}

// ---------------------------------------------------------------------------
// Pre-pass (LDS-free, no barrier; best measured R8): stored [N][256] fp32 ->
// per-32-key-tile fragment blob (32 KB), 32x32x16 MFMA fragment layouts
// (lane l, j = 0..7):
//   K region (fp16 RTZ, PRE-SCALED by log2e; main does p = exp2(S) with M0
//   folded into the accumulator init):
//     pos (s*64 + l)*8 + j  <-  log2e * stored[t*32 + (l&31)][16*s + (l>>5)*8 + j]
//   V region (bf16 -- NOT fp16: P feeds PV and its dynamic range hits fp16's
//   subnormal cliff; bf16 shares fp32 exponent range):
//     pos 8192 + ((dn*2+ks)*64 + l)*8 + j
//         <-  stored[t*32 + 16*ks + (l>>5)*8 + j][32*dn + (l&31)]
// Runs at FULL occupancy standalone (R10 lesson: fusing it into main's
// 8-waves/CU regime made it ~4x slower -- keep the kernels separate).
// ---------------------------------------------------------------------------
__global__ __launch_bounds__(512) void prepass(const float* __restrict__ stored,
                                               unsigned short* __restrict__ frag) {
    const int tid = threadIdx.x;
    const int t = blockIdx.x;
    const float* src = stored + (size_t)t * 32 * 256;
    unsigned short* out = frag + (size_t)t * TILE_USHORTS;
    // K region (fp16, x log2e): 1024 cells of 16B, cell ck = (s, lane)
#pragma unroll
    for (int i = 0; i < 2; ++i) {
        int ck = i * 512 + tid;
        int l = ck & 63, s = ck >> 6;
        int key = l & 31, h = l >> 5;
        int d0 = s * 16 + h * 8;
        const float* p = src + key * 256 + d0;
        f32x4 a = *(const f32x4*)p;
        f32x4 b = *(const f32x4*)(p + 4);
        union { uint4 v; unsigned e[4]; } o;
        o.e[0] = pkrtz(a[0] * LOG2E, a[1] * LOG2E);
        o.e[1] = pkrtz(a[2] * LOG2E, a[3] * LOG2E);
        o.e[2] = pkrtz(b[0] * LOG2E, b[1] * LOG2E);
        o.e[3] = pkrtz(b[2] * LOG2E, b[3] * LOG2E);
        *(uint4*)(out + ck * 8) = o.v;
    }
    // V region (bf16): 1024 cells, cell cv = (dn, ks, lane)
#pragma unroll
    for (int i = 0; i < 2; ++i) {
        int cv = i * 512 + tid;
        int l = cv & 63, blkv = cv >> 6;
        int dn = blkv >> 1, ks = blkv & 1;
        int colv = l & 31, h = l >> 5;
        int d = dn * 32 + colv;
        int k0 = ks * 16 + h * 8;
        union { uint4 v; unsigned e[4]; } o;
#pragma unroll
        for (int j2 = 0; j2 < 4; ++j2) {
            float v0 = src[(k0 + 2 * j2) * 256 + d];
            float v1 = src[(k0 + 2 * j2 + 1) * 256 + d];
            o.e[j2] = cvt_pk_bf16(v0, v1);      // lo=v0, hi=v1
        }
        *(uint4*)(out + 8192 + cv * 8) = o.v;
    }
}

// ---------------------------------------------------------------------------
// Main: grid 512 (2 blocks/CU), 4 waves x 32 queries = 128 q/block.
// FROZEN best schedule (269-275us across 6 structural probes): barrier ->
// prefetch(it+1) via gl_lds(16B) -> QK(it) [S init=-M0L, K pre-scaled by
// log2e] -> softmax half0 -> PV-A -> softmax half1 -> PV-B. Softmax fully
// in-register (cvt_pk+permlane). Structural pin: per-CU-iter MFMA 2048cyc +
// LDS 2560cyc vs 5060 window ~= the serial sum; overlap needs >1 MFMA/LDS-read
// or more waves -- both blocked by the 256-reg/wave wall (R2/R3/R7 regressed).
// ---------------------------------------------------------------------------
__global__ __launch_bounds__(256, 2)
void hopfield_main(const float* __restrict__ x,
                   const unsigned short* __restrict__ frag,
                   unsigned short* __restrict__ partOb,
                   float* __restrict__ partl) {
    __shared__ __align__(16) unsigned short Kb[2][8192];   // 2 x 16 KB
    __shared__ __align__(16) unsigned short Vb[2][8192];   // 2 x 16 KB

    const int tid = threadIdx.x;
    const int wave = tid >> 6, lane = tid & 63;
    const int col = lane & 31, hf = lane >> 5;
    const int blk = blockIdx.x;
    const int chunk = blk & 31, qb = blk >> 5;
    const int q0w = qb * 128 + wave * 32;
    const unsigned short* fbase = frag + (size_t)chunk * NITER * TILE_USHORTS;

    // ---- x fragments (fp16, B-operand layout: X[q=col][d=16s+8*hf+j]) ----
    half8 xf[16];
    float ss = 0.f;
    {
        const float* xr = x + (size_t)(q0w + col) * 256 + hf * 8;
#pragma unroll
        for (int s = 0; s < 16; ++s) {
            f32x4 a = *(const f32x4*)(xr + s * 16);
            f32x4 b = *(const f32x4*)(xr + s * 16 + 4);
            union { half8 v; _Float16 e[8]; } h;
#pragma unroll
            for (int j = 0; j < 4; ++j) {
                h.e[j] = (_Float16)a[j]; h.e[4 + j] = (_Float16)b[j];
                ss += a[j] * a[j] + b[j] * b[j];
            }
            xf[s] = h.v;
        }
    }
    ss += __shfl_xor(ss, 32);                 // lane covers 128 dims; fold halves
    const float negM0L = -(4.9f * sqrtf(ss) * LOG2E);  // S-accumulator init

    f32x16 O[8];
    const f32x16 z16 = {0.f,0.f,0.f,0.f,0.f,0.f,0.f,0.f,
                        0.f,0.f,0.f,0.f,0.f,0.f,0.f,0.f};
#pragma unroll
    for (int dn = 0; dn < 8; ++dn) O[dn] = z16;
    float lacc = 0.f;

    // preload K(0), V(0) into buffer 0 (16 x 1KB chunks each; wave w does 4)
#pragma unroll
    for (int j = 0; j < 4; ++j) {
        int off = (wave * 4 + j) * 512 + lane * 8;
        gl_lds16(fbase + off, &Kb[0][off]);
        gl_lds16(fbase + 8192 + off, &Vb[0][off]);
    }

#pragma unroll 1
    for (int it = 0; it < NITER; ++it) {
        __syncthreads();   // K(it),V(it) staged; prev iter's readers done

        if (it + 1 < NITER) {
            const unsigned short* nbase = fbase + (size_t)(it + 1) * TILE_USHORTS;
#pragma unroll
            for (int j = 0; j < 4; ++j) {
                int off = (wave * 4 + j) * 512 + lane * 8;
                gl_lds16(nbase + off, &Kb[(it + 1) & 1][off]);
                gl_lds16(nbase + 8192 + off, &Vb[(it + 1) & 1][off]);
            }
        }

        const unsigned short* K = Kb[it & 1];
        const unsigned short* V = Vb[it & 1];

        // ---- QK(it): S^T[32k][32q]; S init = -M0L (shift folded in) ----
        f32x16 S;
#pragma unroll
        for (int r = 0; r < 16; ++r) S[r] = negM0L;
        __builtin_amdgcn_s_setprio(1);
#pragma unroll
        for (int s = 0; s < 16; ++s) {
            half8 af = *(const half8*)(K + (s * 64 + lane) * 8);
            S = __builtin_amdgcn_mfma_f32_32x32x16_f16(af, xf[s], S, 0, 0, 0);
        }
        __builtin_amdgcn_s_setprio(0);

        // ---- softmax half0: keys 0..15 (S[0..7]) -> pa0 ----
        // w[r2] packs keys {2*(r2&1)+8*(r2>>1)+4*hf, +1}; permlane32_swap(a,b)
        // -> a'=(a_lo,b_lo), b'=(a_hi,b_hi): regs 0..3 of pa exactly (verified R1).
        float p0[8];
#pragma unroll
        for (int r = 0; r < 8; ++r) p0[r] = __builtin_amdgcn_exp2f(S[r]);
        lacc += ((p0[0] + p0[1]) + (p0[2] + p0[3])) + ((p0[4] + p0[5]) + (p0[6] + p0[7]));
        unsigned w0 = cvt_pk_bf16(p0[0], p0[1]);
        unsigned w1 = cvt_pk_bf16(p0[2], p0[3]);
        unsigned w2 = cvt_pk_bf16(p0[4], p0[5]);
        unsigned w3 = cvt_pk_bf16(p0[6], p0[7]);
        asm volatile("v_permlane32_swap_b32 %0, %1" : "+v"(w0), "+v"(w2));
        asm volatile("v_permlane32_swap_b32 %0, %1" : "+v"(w1), "+v"(w3));
        union { bf16x8 v; unsigned u[4]; } A0;
        A0.u[0] = w0; A0.u[1] = w1; A0.u[2] = w2; A0.u[3] = w3;
        bf16x8 pa0 = A0.v;

        // ---- PV-A: ks=0 V-frags; softmax half1 VALU overlaps this MFMA run --
        __builtin_amdgcn_s_setprio(1);
#pragma unroll
        for (int dn = 0; dn < 8; ++dn) {
            bf16x8 bv0 = *(const bf16x8*)(V + ((dn * 2 + 0) * 64 + lane) * 8);
            O[dn] = __builtin_amdgcn_mfma_f32_32x32x16_bf16(pa0, bv0, O[dn], 0, 0, 0);
        }
        __builtin_amdgcn_s_setprio(0);

        // ---- softmax half1: keys 16..31 (S[8..15]) -> pa1 ----
        float p1[8];
#pragma unroll
        for (int r = 0; r < 8; ++r) p1[r] = __builtin_amdgcn_exp2f(S[8 + r]);
        lacc += ((p1[0] + p1[1]) + (p1[2] + p1[3])) + ((p1[4] + p1[5]) + (p1[6] + p1[7]));
        unsigned w4 = cvt_pk_bf16(p1[0], p1[1]);
        unsigned w5 = cvt_pk_bf16(p1[2], p1[3]);
        unsigned w6 = cvt_pk_bf16(p1[4], p1[5]);
        unsigned w7 = cvt_pk_bf16(p1[6], p1[7]);
        asm volatile("v_permlane32_swap_b32 %0, %1" : "+v"(w4), "+v"(w6));
        asm volatile("v_permlane32_swap_b32 %0, %1" : "+v"(w5), "+v"(w7));
        union { bf16x8 v; unsigned u[4]; } A1;
        A1.u[0] = w4; A1.u[1] = w5; A1.u[2] = w6; A1.u[3] = w7;
        bf16x8 pa1 = A1.v;

        // ---- PV-B: ks=1 V-frags ----
        __builtin_amdgcn_s_setprio(1);
#pragma unroll
        for (int dn = 0; dn < 8; ++dn) {
            bf16x8 bv1 = *(const bf16x8*)(V + ((dn * 2 + 1) * 64 + lane) * 8);
            O[dn] = __builtin_amdgcn_mfma_f32_32x32x16_bf16(pa1, bv1, O[dn], 0, 0, 0);
        }
        __builtin_amdgcn_s_setprio(0);
    }

    // ---- epilogue: l then O as bf16 (row q = (r&3)+8*(r>>2)+4*hf, col d) ----
    lacc += __shfl_xor(lacc, 32);
    if (lane < 32)
        partl[(size_t)chunk * B_Q + q0w + lane] = lacc;

#pragma unroll
    for (int dn = 0; dn < 8; ++dn)
#pragma unroll
        for (int r = 0; r < 16; ++r) {
            int qrow = (r & 3) + 8 * (r >> 2) + 4 * hf;
            partOb[((size_t)chunk * B_Q + q0w + qrow) * 256 + dn * 32 + col] = f2bf(O[dn][r]);
        }
}

// ---------------------------------------------------------------------------
// Combine: plain sums (common M0 per query across chunks), bf16 partials.
// grid 512 x 256: block = 4 q x 64 threads; thread = 4 consecutive d.
// ---------------------------------------------------------------------------
__global__ __launch_bounds__(256) void combine_kernel(const unsigned short* __restrict__ partOb,
                                                      const float* __restrict__ partl,
                                                      float* __restrict__ out) {
    const int tid = threadIdx.x;
    const int ql = tid >> 6;                 // 0..3
    const int q  = blockIdx.x * 4 + ql;
    const int d0 = (tid & 63) * 4;
    float L = 0.f;
#pragma unroll
    for (int c = 0; c < NCHUNK; ++c) L += partl[(size_t)c * B_Q + q];
    float acc[4] = {0.f, 0.f, 0.f, 0.f};
#pragma unroll 4
    for (int c = 0; c < NCHUNK; ++c) {
        bf16x4 v = *(const bf16x4*)(partOb + ((size_t)c * B_Q + q) * 256 + d0);
#pragma unroll
        for (int j = 0; j < 4; ++j) {
            unsigned u = (unsigned)(unsigned short)v[j] << 16;
            acc[j] += __builtin_bit_cast(float, u);
        }
    }
    const float invL = 1.f / L;
    f32x4 o = {acc[0] * invL, acc[1] * invL, acc[2] * invL, acc[3] * invL};
    *(f32x4*)(out + (size_t)q * 256 + d0) = o;
}

// ---------------------------------------------------------------------------
extern "C" void kernel_launch(void* const* d_in, const int* in_sizes, int n_in,
                              void* d_out, int out_size, void* d_ws, size_t ws_size,
                              hipStream_t stream) {
    const float* x      = (const float*)d_in[0];
    const float* stored = (const float*)d_in[1];
    float* out = (float*)d_out;

    char* wsb = (char*)d_ws;
    unsigned short* frag   = (unsigned short*)wsb;                       // 128 MiB
    unsigned short* partOb = (unsigned short*)(wsb + (size_t)134217728); // 32 MiB (bf16)
    float* partl = (float*)(wsb + (size_t)134217728 + 33554432);         // 256 KiB

    prepass<<<NTILES, 512, 0, stream>>>(stored, frag);
    hopfield_main<<<512, 256, 0, stream>>>(x, frag, partOb, partl);
    combine_kernel<<<512, 256, 0, stream>>>(partOb, partl, out);
}